// Round 4
// baseline (298.906 us; speedup 1.0000x reference)
//
#include <hip/hip_runtime.h>
#include <math.h>

// ---------------------------------------------------------------------------
// GMM log-likelihood, N=2M x D=16, K=32, out = mean_n logsumexp_k loglik[n,k]
//
// loglik[n,k] = sum_{ij} (-0.5 P_ij) x_i x_j + (P mu)_i x_i + c_k  (log2 dom.)
// LINEAR in phi(x) = [ x_i*x_j (256), x_i (16), 1 ] -> 18 K16-chunks of one
// chained mfma_f32_32x32x16_f16 (M=32 = all comps; c_k folded in as chunk 17).
// C layout (HW-verified): col=lane&31 (point), row=(reg&3)+8*(reg>>2)+4*(lane>>5).
// Lane pair (l, l^32) holds all 32 comps of a point; combined via
// v_permlane32_swap (VALU-only).
//
// R10: R9 (coalesced+LDS transpose) regressed 50->75us -> gather/L1 theory
// dead; LDS staging reverted. Full-record re-read: OccupancyPercent was ~25%
// (= 8 waves/CU = 2 waves/SIMD) in EVERY round; R7's (256,3) was not met by
// the allocator (live set ~150 regs) and grid 768 just serialized 1.5 rounds.
// The TLP lever was never actually pulled, while nothing is saturated
// (MfmaUtil 19%, VALUBusy 25%, HBM 10%) -> latency-bound, 2 chains/SIMD.
// This round: cut live set to ~124-132 (single acc, tree epilogue, no LDS,
// keep R7's proven gather+depth-1-prefetch loop), request (256,4) = 128-reg
// budget -> 4 waves/SIMD, and stream GRID=2048 blocks (counter-based fused
// reduction makes any grid correct; per-block Wf reload is L2/L3-cached).
// Predict: main occupancy >=37%, dur ~30-35us, total ~185. Spill tell:
// WRITE_SIZE >> 1MB on main's dispatch -> revert to (256,2).
// ---------------------------------------------------------------------------

#define LOG_2PI 1.8378770664093453f
#define INV_LN2 1.4426950408889634f
#define LN2_D   0.6931471805599453

typedef float    float4v __attribute__((ext_vector_type(4)));
typedef float    f32x16  __attribute__((ext_vector_type(16)));
typedef _Float16 f16x8   __attribute__((ext_vector_type(8)));
typedef _Float16 f16x2   __attribute__((ext_vector_type(2)));

union H8 { f16x8 h8; f16x2 h2[4]; };

#if __has_builtin(__builtin_amdgcn_exp2f)
#define EXP2F(x) __builtin_amdgcn_exp2f(x)
#else
#define EXP2F(x) exp2f(x)
#endif
#if __has_builtin(__builtin_amdgcn_logf)
#define LOG2F(x) __builtin_amdgcn_logf(x)
#else
#define LOG2F(x) log2f(x)
#endif

static __device__ __forceinline__ f16x2 pk2(float a, float b) {
#if __has_builtin(__builtin_amdgcn_cvt_pkrtz)
  return __builtin_bit_cast(f16x2, __builtin_amdgcn_cvt_pkrtz(a, b));
#else
  f16x2 r; r[0] = (_Float16)a; r[1] = (_Float16)b; return r;
#endif
}

// value of x in partner lane (lane ^ 32), VALU-only on gfx950
static __device__ __forceinline__ float partner32(float x, bool lo) {
#if __has_builtin(__builtin_amdgcn_permlane32_swap)
  typedef unsigned u32x2 __attribute__((ext_vector_type(2)));
  unsigned u = __builtin_bit_cast(unsigned, x);
  u32x2 r = __builtin_amdgcn_permlane32_swap(u, u, false, false);
  return __builtin_bit_cast(float, lo ? r[1] : r[0]);
#else
  return __shfl_xor(x, 32, 64);
#endif
}

// dword select (works for f16x2 payloads)
static __device__ __forceinline__ f16x2 sel2(bool c, f16x2 a, f16x2 b) {
  unsigned ua = __builtin_bit_cast(unsigned, a);
  unsigned ub = __builtin_bit_cast(unsigned, b);
  return __builtin_bit_cast(f16x2, c ? ua : ub);
}

// ---------------------------------------------------------------------------
// Setup: per component k: cov = A A^T, Cholesky L, Linv, P = Linv^T Linv.
// W in 32x32x16 A-frag order: lane l holds A[m=l&31][k16 = 8*(l>>5)+v],
// chunk c covers feature k = 16c + 8h + v.
// chunks 0..15: (i,j)=(c, 8h+v) -> -0.5/ln2 * P[i][j]
// chunk 16: linear, feature i=8h+v -> (P mu)_i / ln2
// chunk 17: constant, slot (h=0,v=0) -> c2[m]; all other slots 0
// Also zeroes the main-kernel's ticket counter each launch (graph replay).
// ---------------------------------------------------------------------------
__global__ void setup_kernel(const float* __restrict__ means,
                             const float* __restrict__ cov_parts,
                             const float* __restrict__ log_weights,
                             _Float16* __restrict__ W,
                             unsigned* __restrict__ counter)
{
  const int k = blockIdx.x;
  const int i = threadIdx.x;

  if (k == 0 && i == 0) counter[0] = 0u;

  __shared__ float sA[16][17];
  __shared__ float sC[16][17];
  __shared__ float sMu[16];
  __shared__ float sR[16];

  if (i < 16) {
    #pragma unroll
    for (int j = 0; j < 16; ++j) sA[i][j] = cov_parts[(k*16 + i)*16 + j];
    sMu[i] = means[k*16 + i];
  }
  __syncthreads();

  if (i < 16) {
    #pragma unroll
    for (int j = 0; j < 16; ++j) {
      float acc = 0.f;
      #pragma unroll
      for (int l = 0; l < 16; ++l) acc += sA[i][l] * sA[j][l];
      sC[i][j] = acc;
    }
  }
  __syncthreads();

  for (int j = 0; j < 16; ++j) {
    if (i == j) {
      float d = sC[j][j];
      for (int l = 0; l < j; ++l) d -= sC[j][l]*sC[j][l];
      sC[j][j] = sqrtf(d);
    }
    __syncthreads();
    if (i < 16 && i > j) {
      float a = sC[i][j];
      for (int l = 0; l < j; ++l) a -= sC[i][l]*sC[j][l];
      sC[i][j] = a / sC[j][j];
    }
    __syncthreads();
  }

  if (i < 16) {
    float y[16];
    #pragma unroll
    for (int r = 0; r < 16; ++r) {
      float a = (r == i) ? 1.f : 0.f;
      #pragma unroll
      for (int l = 0; l < r; ++l) a -= sC[r][l] * y[l];
      y[r] = a / sC[r][r];
    }
    #pragma unroll
    for (int r = 0; r < 16; ++r) sA[r][i] = y[r];
  }
  __syncthreads();

  if (i < 16) {
    float p[16];
    #pragma unroll
    for (int j = 0; j < 16; ++j) {
      float acc = 0.f;
      #pragma unroll
      for (int l = 0; l < 16; ++l) acc += sA[l][i] * sA[l][j];
      p[j] = acc;
    }
    float ri = 0.f;
    #pragma unroll
    for (int j = 0; j < 16; ++j) ri += p[j] * sMu[j];
    sR[i] = ri;

    #pragma unroll
    for (int j = 0; j < 16; ++j) {
      W[(size_t)(i*64 + (k + 32*(j >> 3)))*8 + (j & 7)] =
          (_Float16)(-0.5f * INV_LN2 * p[j]);
    }
    W[(size_t)(16*64 + (k + 32*(i >> 3)))*8 + (i & 7)] =
        (_Float16)(INV_LN2 * ri);
  }
  __syncthreads();

  if (i == 0) {
    float logdet = 0.f;
    #pragma unroll
    for (int j = 0; j < 16; ++j) logdet += __logf(sC[j][j]);
    float mupmu = 0.f;
    #pragma unroll
    for (int j = 0; j < 16; ++j) mupmu += sMu[j] * sR[j];
    float lw = log_weights[k];
    float c2v = INV_LN2 * (-0.5f*(mupmu + 16.f*LOG_2PI) - logdet + lw*lw);
    #pragma unroll
    for (int v = 0; v < 8; ++v) {
      W[(size_t)(17*64 + k)*8 + v]      = (v == 0) ? (_Float16)c2v : (_Float16)0.f;
      W[(size_t)(17*64 + k + 32)*8 + v] = (_Float16)0.f;
    }
  }
}

// ---------------------------------------------------------------------------
__global__ __launch_bounds__(256, 4) void main_kernel(
    const float* __restrict__ data,
    const _Float16* __restrict__ W,
    float* __restrict__ partials,
    unsigned* __restrict__ counter,
    float* __restrict__ out,
    double scale,
    int ntiles)
{
  const int tid  = (int)threadIdx.x;
  const int lane = tid & 63;
  const int n32  = lane & 31;
  const bool lo  = lane < 32;
  const int gwave  = (int)((blockIdx.x * blockDim.x + tid) >> 6);
  const int nwaves = (int)((gridDim.x * blockDim.x) >> 6);

  // W fragments resident in registers (72 regs; re-read per block, L2/L3 hit)
  f16x8 Wf[18];
  #pragma unroll
  for (int c = 0; c < 18; ++c)
    Wf[c] = *(const f16x8*)(W + (size_t)(c*64 + lane)*8);

  // constant B fragment for the c2 chunk: slot (h=0,v=0) = 1
  H8 bC;
  #pragma unroll
  for (int j = 0; j < 4; ++j) bC.h2[j] = pk2(0.f, 0.f);
  if (lo) bC.h2[0] = pk2(1.f, 0.f);

  float accsum = 0.f;

  // tile t covers points [t*32, t*32+32); lane pair (l, l^32) share point n32
  const char* ptr = (const char*)data + ((size_t)gwave*2048 + (size_t)n32*64);
  const size_t step = (size_t)nwaves * 2048;

  float4v p0, p1, p2, p3;
  if (gwave < ntiles) {
    p0 = *(const float4v*)(ptr);      p1 = *(const float4v*)(ptr + 16);
    p2 = *(const float4v*)(ptr + 32); p3 = *(const float4v*)(ptr + 48);
  }

  for (int t = gwave; t < ntiles; t += nwaves) {
    // convert to f16 pairs: xh[q] = (x[2q], x[2q+1]); frees p* for prefetch
    f16x2 xh[8];
    xh[0] = pk2(p0[0], p0[1]); xh[1] = pk2(p0[2], p0[3]);
    xh[2] = pk2(p1[0], p1[1]); xh[3] = pk2(p1[2], p1[3]);
    xh[4] = pk2(p2[0], p2[1]); xh[5] = pk2(p2[2], p2[3]);
    xh[6] = pk2(p3[0], p3[1]); xh[7] = pk2(p3[2], p3[3]);

    ptr += step;
    if (t + nwaves < ntiles) {          // wave-uniform prefetch of next tile
      p0 = *(const float4v*)(ptr);      p1 = *(const float4v*)(ptr + 16);
      p2 = *(const float4v*)(ptr + 32); p3 = *(const float4v*)(ptr + 48);
    }

    // second factors for this lane half: xs[j] = xh[4h + j]
    f16x2 xs[4];
    #pragma unroll
    for (int j = 0; j < 4; ++j) xs[j] = sel2(lo, xh[j], xh[4+j]);

    f32x16 acc;
    #pragma unroll
    for (int r = 0; r < 16; ++r) acc[r] = 0.f;

    #pragma unroll
    for (int c = 0; c < 16; ++c) {
      _Float16 xi = xh[c >> 1][c & 1];
      H8 b;
      #pragma unroll
      for (int j = 0; j < 4; ++j) b.h2[j] = xs[j] * xi;  // v_pk_mul_f16
      acc = __builtin_amdgcn_mfma_f32_32x32x16_f16(Wf[c], b.h8, acc, 0, 0, 0);
    }
    {   // linear chunk
      H8 b;
      #pragma unroll
      for (int j = 0; j < 4; ++j) b.h2[j] = xs[j];
      acc = __builtin_amdgcn_mfma_f32_32x32x16_f16(Wf[16], b.h8, acc, 0, 0, 0);
    }
    // c2 chunk
    acc = __builtin_amdgcn_mfma_f32_32x32x16_f16(Wf[17], bC.h8, acc, 0, 0, 0);

    // epilogue: logsumexp (log2 domain), tree-shaped to shorten dep chains
    float mx0 = fmaxf(acc[0],  acc[8]);
    float mx1 = fmaxf(acc[1],  acc[9]);
    float mx2 = fmaxf(acc[2],  acc[10]);
    float mx3 = fmaxf(acc[3],  acc[11]);
    float mx4 = fmaxf(acc[4],  acc[12]);
    float mx5 = fmaxf(acc[5],  acc[13]);
    float mx6 = fmaxf(acc[6],  acc[14]);
    float mx7 = fmaxf(acc[7],  acc[15]);
    mx0 = fmaxf(mx0, mx4); mx1 = fmaxf(mx1, mx5);
    mx2 = fmaxf(mx2, mx6); mx3 = fmaxf(mx3, mx7);
    mx0 = fmaxf(mx0, mx2); mx1 = fmaxf(mx1, mx3);
    float m = fmaxf(mx0, mx1);
    m = fmaxf(m, partner32(m, lo));

    float e0  = EXP2F(acc[0]  - m), e1  = EXP2F(acc[1]  - m);
    float e2  = EXP2F(acc[2]  - m), e3  = EXP2F(acc[3]  - m);
    float e4  = EXP2F(acc[4]  - m), e5  = EXP2F(acc[5]  - m);
    float e6  = EXP2F(acc[6]  - m), e7  = EXP2F(acc[7]  - m);
    float e8  = EXP2F(acc[8]  - m), e9  = EXP2F(acc[9]  - m);
    float e10 = EXP2F(acc[10] - m), e11 = EXP2F(acc[11] - m);
    float e12 = EXP2F(acc[12] - m), e13 = EXP2F(acc[13] - m);
    float e14 = EXP2F(acc[14] - m), e15 = EXP2F(acc[15] - m);
    e0 += e8;  e1 += e9;  e2 += e10; e3 += e11;
    e4 += e12; e5 += e13; e6 += e14; e7 += e15;
    e0 += e4;  e1 += e5;  e2 += e6;  e3 += e7;
    e0 += e2;  e1 += e3;
    float s = e0 + e1;
    s += partner32(s, lo);
    accsum += m + LOG2F(s);
  }

  #pragma unroll
  for (int off = 1; off <= 32; off <<= 1)
    accsum += __shfl_xor(accsum, off, 64);

  __shared__ float wsum[4];
  __shared__ int isLast;
  const int wid = tid >> 6;
  if ((tid & 63) == 0) wsum[wid] = accsum;
  __syncthreads();
  if (tid == 0) {
    partials[blockIdx.x] = wsum[0] + wsum[1] + wsum[2] + wsum[3];
    __threadfence();                       // release partials (device scope)
    unsigned old = atomicAdd(counter, 1u); // device-scope ticket
    isLast = (old == gridDim.x - 1) ? 1 : 0;
  }
  __syncthreads();

  if (isLast) {
    __threadfence();                       // acquire all partials
    __shared__ double sd[256];
    double a = 0.0;
    for (int idx = tid; idx < (int)gridDim.x; idx += 256)
      a += (double)partials[idx];
    sd[tid] = a;
    __syncthreads();
    for (int s2 = 128; s2 > 0; s2 >>= 1) {
      if (tid < s2) sd[tid] += sd[tid + s2];
      __syncthreads();
    }
    if (tid == 0) out[0] = (float)(sd[0] * scale);
  }
}

// ---------------------------------------------------------------------------
extern "C" void kernel_launch(void* const* d_in, const int* in_sizes, int n_in,
                              void* d_out, int out_size, void* d_ws, size_t ws_size,
                              hipStream_t stream)
{
  const float* data        = (const float*)d_in[0];
  const float* means       = (const float*)d_in[1];
  const float* cov_parts   = (const float*)d_in[2];
  const float* log_weights = (const float*)d_in[3];

  const int npts   = in_sizes[0] / 16;
  const int ntiles = npts / 32;        // N = 2,000,000 divisible by 32

  _Float16* W        = (_Float16*)d_ws;                         // 18*64*8 halfs
  float*    partials = (float*)((char*)d_ws + 18432);           // 2048 floats
  unsigned* counter  = (unsigned*)((char*)d_ws + 18432 + 8192); // 1 u32

  const int GRID = 2048, BLOCK = 256;  // stream blocks; counter-reduce is
                                       // correct for any grid
  setup_kernel<<<32, 64, 0, stream>>>(means, cov_parts, log_weights, W, counter);
  main_kernel<<<GRID, BLOCK, 0, stream>>>(data, W, partials, counter,
                                          (float*)d_out,
                                          LN2_D / (2.0 * (double)npts), ntiles);
}

// Round 5
// 217.186 us; speedup vs baseline: 1.3763x; 1.3763x over previous
//
#include <hip/hip_runtime.h>
#include <math.h>

// ---------------------------------------------------------------------------
// GMM log-likelihood, N=2M x D=16, K=32, out = mean_n logsumexp_k loglik[n,k]
//
// loglik[n,k] = sum_{ij} (-0.5 P_ij) x_i x_j + (P mu)_i x_i + c_k  (log2 dom.)
// LINEAR in phi(x) = [ x_i*x_j (256), x_i (16), 1 ] -> 18 K16-chunks of one
// chained mfma_f32_32x32x16_f16 (M=32 = all comps; c_k folded in as chunk 17).
// C layout (HW-verified): col=lane&31 (point), row=(reg&3)+8*(reg>>2)+4*(lane>>5).
// Lane pair (l, l^32) holds all 32 comps of a point; combined via
// v_permlane32_swap (VALU-only).
//
// R11: R10's (256,4) spilled Wf (VGPR_Count=64, WRITE_SIZE=8.3MB, 149us) ->
// TLP via register-squeeze is a dead end; revert (256,2)/grid 512.
// Standing facts: ~500 issue-cyc vs ~3900 wall-cyc per tile (87% stall),
// HBM 10% / MFMA 17% / VALU 25%. R9's "coalesced was worse" was likely
// poisoned by a vmcnt(0) drain between its ds_write and a fresh gload, so
// the gather-request theory was never fairly tested. Current gather:
// 4 instr x 32 unique 64B-line requests = 128 line-transactions/tile/wave,
// with lanes l and l^32 loading DUPLICATE bytes.
// Fix (zero-shuffle): lo lane loads its point's first 32B (= exactly its
// own xs half), hi lane the second 32B -> 2 VMEM instr, 64 line-transactions
// per tile (2x fewer), no duplication. Full 16-feature xi vector recovered
// via 4 permlane32_swap + 8 cndmask (VALU-only). Live set drops ~12 regs.
// Everything else = proven best (depth-1 prefetch, single acc, tree
// epilogue, fused counter-reduction).
// Predict: main ~30-35us & total ~185-190 if request-rate theory right;
// main ~50us unchanged -> theory dead, declare roofline next round.
// ---------------------------------------------------------------------------

#define LOG_2PI 1.8378770664093453f
#define INV_LN2 1.4426950408889634f
#define LN2_D   0.6931471805599453

typedef float    float4v __attribute__((ext_vector_type(4)));
typedef float    f32x16  __attribute__((ext_vector_type(16)));
typedef _Float16 f16x8   __attribute__((ext_vector_type(8)));
typedef _Float16 f16x2   __attribute__((ext_vector_type(2)));
typedef unsigned u32x2   __attribute__((ext_vector_type(2)));

union H8 { f16x8 h8; f16x2 h2[4]; };

#if __has_builtin(__builtin_amdgcn_exp2f)
#define EXP2F(x) __builtin_amdgcn_exp2f(x)
#else
#define EXP2F(x) exp2f(x)
#endif
#if __has_builtin(__builtin_amdgcn_logf)
#define LOG2F(x) __builtin_amdgcn_logf(x)
#else
#define LOG2F(x) log2f(x)
#endif

static __device__ __forceinline__ f16x2 pk2(float a, float b) {
#if __has_builtin(__builtin_amdgcn_cvt_pkrtz)
  return __builtin_bit_cast(f16x2, __builtin_amdgcn_cvt_pkrtz(a, b));
#else
  f16x2 r; r[0] = (_Float16)a; r[1] = (_Float16)b; return r;
#endif
}

// partner-lane (lane ^ 32) value, VALU-only on gfx950
static __device__ __forceinline__ float partner32(float x, bool lo) {
#if __has_builtin(__builtin_amdgcn_permlane32_swap)
  unsigned u = __builtin_bit_cast(unsigned, x);
  u32x2 r = __builtin_amdgcn_permlane32_swap(u, u, false, false);
  return __builtin_bit_cast(float, lo ? r[1] : r[0]);
#else
  return __shfl_xor(x, 32, 64);
#endif
}

static __device__ __forceinline__ f16x2 partner32h(f16x2 x, bool lo) {
#if __has_builtin(__builtin_amdgcn_permlane32_swap)
  unsigned u = __builtin_bit_cast(unsigned, x);
  u32x2 r = __builtin_amdgcn_permlane32_swap(u, u, false, false);
  return __builtin_bit_cast(f16x2, lo ? r[1] : r[0]);
#else
  unsigned u = __builtin_bit_cast(unsigned, x);
  u = __shfl_xor((int)u, 32, 64);
  return __builtin_bit_cast(f16x2, u);
#endif
}

// dword select (works for f16x2 payloads)
static __device__ __forceinline__ f16x2 sel2(bool c, f16x2 a, f16x2 b) {
  unsigned ua = __builtin_bit_cast(unsigned, a);
  unsigned ub = __builtin_bit_cast(unsigned, b);
  return __builtin_bit_cast(f16x2, c ? ua : ub);
}

// ---------------------------------------------------------------------------
// Setup: per component k: cov = A A^T, Cholesky L, Linv, P = Linv^T Linv.
// W in 32x32x16 A-frag order: lane l holds A[m=l&31][k16 = 8*(l>>5)+v],
// chunk c covers feature k = 16c + 8h + v.
// chunks 0..15: (i,j)=(c, 8h+v) -> -0.5/ln2 * P[i][j]
// chunk 16: linear, feature i=8h+v -> (P mu)_i / ln2
// chunk 17: constant, slot (h=0,v=0) -> c2[m]; all other slots 0
// Also zeroes the main-kernel's ticket counter each launch (graph replay).
// ---------------------------------------------------------------------------
__global__ void setup_kernel(const float* __restrict__ means,
                             const float* __restrict__ cov_parts,
                             const float* __restrict__ log_weights,
                             _Float16* __restrict__ W,
                             unsigned* __restrict__ counter)
{
  const int k = blockIdx.x;
  const int i = threadIdx.x;

  if (k == 0 && i == 0) counter[0] = 0u;

  __shared__ float sA[16][17];
  __shared__ float sC[16][17];
  __shared__ float sMu[16];
  __shared__ float sR[16];

  if (i < 16) {
    #pragma unroll
    for (int j = 0; j < 16; ++j) sA[i][j] = cov_parts[(k*16 + i)*16 + j];
    sMu[i] = means[k*16 + i];
  }
  __syncthreads();

  if (i < 16) {
    #pragma unroll
    for (int j = 0; j < 16; ++j) {
      float acc = 0.f;
      #pragma unroll
      for (int l = 0; l < 16; ++l) acc += sA[i][l] * sA[j][l];
      sC[i][j] = acc;
    }
  }
  __syncthreads();

  for (int j = 0; j < 16; ++j) {
    if (i == j) {
      float d = sC[j][j];
      for (int l = 0; l < j; ++l) d -= sC[j][l]*sC[j][l];
      sC[j][j] = sqrtf(d);
    }
    __syncthreads();
    if (i < 16 && i > j) {
      float a = sC[i][j];
      for (int l = 0; l < j; ++l) a -= sC[i][l]*sC[j][l];
      sC[i][j] = a / sC[j][j];
    }
    __syncthreads();
  }

  if (i < 16) {
    float y[16];
    #pragma unroll
    for (int r = 0; r < 16; ++r) {
      float a = (r == i) ? 1.f : 0.f;
      #pragma unroll
      for (int l = 0; l < r; ++l) a -= sC[r][l] * y[l];
      y[r] = a / sC[r][r];
    }
    #pragma unroll
    for (int r = 0; r < 16; ++r) sA[r][i] = y[r];
  }
  __syncthreads();

  if (i < 16) {
    float p[16];
    #pragma unroll
    for (int j = 0; j < 16; ++j) {
      float acc = 0.f;
      #pragma unroll
      for (int l = 0; l < 16; ++l) acc += sA[l][i] * sA[l][j];
      p[j] = acc;
    }
    float ri = 0.f;
    #pragma unroll
    for (int j = 0; j < 16; ++j) ri += p[j] * sMu[j];
    sR[i] = ri;

    #pragma unroll
    for (int j = 0; j < 16; ++j) {
      W[(size_t)(i*64 + (k + 32*(j >> 3)))*8 + (j & 7)] =
          (_Float16)(-0.5f * INV_LN2 * p[j]);
    }
    W[(size_t)(16*64 + (k + 32*(i >> 3)))*8 + (i & 7)] =
        (_Float16)(INV_LN2 * ri);
  }
  __syncthreads();

  if (i == 0) {
    float logdet = 0.f;
    #pragma unroll
    for (int j = 0; j < 16; ++j) logdet += __logf(sC[j][j]);
    float mupmu = 0.f;
    #pragma unroll
    for (int j = 0; j < 16; ++j) mupmu += sMu[j] * sR[j];
    float lw = log_weights[k];
    float c2v = INV_LN2 * (-0.5f*(mupmu + 16.f*LOG_2PI) - logdet + lw*lw);
    #pragma unroll
    for (int v = 0; v < 8; ++v) {
      W[(size_t)(17*64 + k)*8 + v]      = (v == 0) ? (_Float16)c2v : (_Float16)0.f;
      W[(size_t)(17*64 + k + 32)*8 + v] = (_Float16)0.f;
    }
  }
}

// ---------------------------------------------------------------------------
__global__ __launch_bounds__(256, 2) void main_kernel(
    const float* __restrict__ data,
    const _Float16* __restrict__ W,
    float* __restrict__ partials,
    unsigned* __restrict__ counter,
    float* __restrict__ out,
    double scale,
    int ntiles)
{
  const int tid  = (int)threadIdx.x;
  const int lane = tid & 63;
  const int n32  = lane & 31;
  const bool lo  = lane < 32;
  const int gwave  = (int)((blockIdx.x * blockDim.x + tid) >> 6);
  const int nwaves = (int)((gridDim.x * blockDim.x) >> 6);

  // W fragments resident in registers for the whole kernel (72 regs)
  f16x8 Wf[18];
  #pragma unroll
  for (int c = 0; c < 18; ++c)
    Wf[c] = *(const f16x8*)(W + (size_t)(c*64 + lane)*8);

  // constant B fragment for the c2 chunk: slot (h=0,v=0) = 1
  H8 bC;
  #pragma unroll
  for (int j = 0; j < 4; ++j) bC.h2[j] = pk2(0.f, 0.f);
  if (lo) bC.h2[0] = pk2(1.f, 0.f);

  float accsum = 0.f;

  // tile t covers points [t*32, t*32+32). Lane l owns point n32; lo lane
  // loads its point's first 32 B (features 0-7), hi lane the second 32 B
  // (features 8-15). 2 VMEM instr/tile, 64 line-transactions, no duplicate
  // bytes (vs 4 instr / 128 transactions before).
  const char* ptr = (const char*)data
      + ((size_t)gwave*2048 + (size_t)n32*64 + (size_t)(lo ? 0 : 32));
  const size_t step = (size_t)nwaves * 2048;

  float4v q0, q1;
  if (gwave < ntiles) {
    q0 = *(const float4v*)(ptr);
    q1 = *(const float4v*)(ptr + 16);
  }

  for (int t = gwave; t < ntiles; t += nwaves) {
    // own half -> f16 pairs: xs[j] = features (8h + 2j, 8h + 2j+1)
    f16x2 xs0 = pk2(q0[0], q0[1]);
    f16x2 xs1 = pk2(q0[2], q0[3]);
    f16x2 xs2 = pk2(q1[0], q1[1]);
    f16x2 xs3 = pk2(q1[2], q1[3]);

    ptr += step;
    if (t + nwaves < ntiles) {          // depth-1 prefetch of next tile
      q0 = *(const float4v*)(ptr);
      q1 = *(const float4v*)(ptr + 16);
    }

    // partner's half via permlane32_swap (VALU-only), then order into
    // feature-0-7 (xlo) / feature-8-15 (xhi) views for the xi scalars
    f16x2 ot0 = partner32h(xs0, lo);
    f16x2 ot1 = partner32h(xs1, lo);
    f16x2 ot2 = partner32h(xs2, lo);
    f16x2 ot3 = partner32h(xs3, lo);

    f16x2 xlo[4], xhi[4];
    xlo[0] = sel2(lo, xs0, ot0); xhi[0] = sel2(lo, ot0, xs0);
    xlo[1] = sel2(lo, xs1, ot1); xhi[1] = sel2(lo, ot1, xs1);
    xlo[2] = sel2(lo, xs2, ot2); xhi[2] = sel2(lo, ot2, xs2);
    xlo[3] = sel2(lo, xs3, ot3); xhi[3] = sel2(lo, ot3, xs3);

    f32x16 acc;
    #pragma unroll
    for (int r = 0; r < 16; ++r) acc[r] = 0.f;

    #pragma unroll
    for (int c = 0; c < 16; ++c) {
      _Float16 xi = (c < 8) ? xlo[c >> 1][c & 1] : xhi[(c >> 1) - 4][c & 1];
      H8 b;
      b.h2[0] = xs0 * xi;   // v_pk_mul_f16
      b.h2[1] = xs1 * xi;
      b.h2[2] = xs2 * xi;
      b.h2[3] = xs3 * xi;
      acc = __builtin_amdgcn_mfma_f32_32x32x16_f16(Wf[c], b.h8, acc, 0, 0, 0);
    }
    {   // linear chunk
      H8 b;
      b.h2[0] = xs0; b.h2[1] = xs1; b.h2[2] = xs2; b.h2[3] = xs3;
      acc = __builtin_amdgcn_mfma_f32_32x32x16_f16(Wf[16], b.h8, acc, 0, 0, 0);
    }
    // c2 chunk
    acc = __builtin_amdgcn_mfma_f32_32x32x16_f16(Wf[17], bC.h8, acc, 0, 0, 0);

    // epilogue: logsumexp (log2 domain), tree-shaped to shorten dep chains
    float mx0 = fmaxf(acc[0],  acc[8]);
    float mx1 = fmaxf(acc[1],  acc[9]);
    float mx2 = fmaxf(acc[2],  acc[10]);
    float mx3 = fmaxf(acc[3],  acc[11]);
    float mx4 = fmaxf(acc[4],  acc[12]);
    float mx5 = fmaxf(acc[5],  acc[13]);
    float mx6 = fmaxf(acc[6],  acc[14]);
    float mx7 = fmaxf(acc[7],  acc[15]);
    mx0 = fmaxf(mx0, mx4); mx1 = fmaxf(mx1, mx5);
    mx2 = fmaxf(mx2, mx6); mx3 = fmaxf(mx3, mx7);
    mx0 = fmaxf(mx0, mx2); mx1 = fmaxf(mx1, mx3);
    float m = fmaxf(mx0, mx1);
    m = fmaxf(m, partner32(m, lo));

    float e0  = EXP2F(acc[0]  - m), e1  = EXP2F(acc[1]  - m);
    float e2  = EXP2F(acc[2]  - m), e3  = EXP2F(acc[3]  - m);
    float e4  = EXP2F(acc[4]  - m), e5  = EXP2F(acc[5]  - m);
    float e6  = EXP2F(acc[6]  - m), e7  = EXP2F(acc[7]  - m);
    float e8  = EXP2F(acc[8]  - m), e9  = EXP2F(acc[9]  - m);
    float e10 = EXP2F(acc[10] - m), e11 = EXP2F(acc[11] - m);
    float e12 = EXP2F(acc[12] - m), e13 = EXP2F(acc[13] - m);
    float e14 = EXP2F(acc[14] - m), e15 = EXP2F(acc[15] - m);
    e0 += e8;  e1 += e9;  e2 += e10; e3 += e11;
    e4 += e12; e5 += e13; e6 += e14; e7 += e15;
    e0 += e4;  e1 += e5;  e2 += e6;  e3 += e7;
    e0 += e2;  e1 += e3;
    float s = e0 + e1;
    s += partner32(s, lo);
    accsum += m + LOG2F(s);
  }

  #pragma unroll
  for (int off = 1; off <= 32; off <<= 1)
    accsum += __shfl_xor(accsum, off, 64);

  __shared__ float wsum[4];
  __shared__ int isLast;
  const int wid = tid >> 6;
  if ((tid & 63) == 0) wsum[wid] = accsum;
  __syncthreads();
  if (tid == 0) {
    partials[blockIdx.x] = wsum[0] + wsum[1] + wsum[2] + wsum[3];
    __threadfence();                       // release partials (device scope)
    unsigned old = atomicAdd(counter, 1u); // device-scope ticket
    isLast = (old == gridDim.x - 1) ? 1 : 0;
  }
  __syncthreads();

  if (isLast) {
    __threadfence();                       // acquire all partials
    __shared__ double sd[256];
    double a = 0.0;
    for (int idx = tid; idx < (int)gridDim.x; idx += 256)
      a += (double)partials[idx];
    sd[tid] = a;
    __syncthreads();
    for (int s2 = 128; s2 > 0; s2 >>= 1) {
      if (tid < s2) sd[tid] += sd[tid + s2];
      __syncthreads();
    }
    if (tid == 0) out[0] = (float)(sd[0] * scale);
  }
}

// ---------------------------------------------------------------------------
extern "C" void kernel_launch(void* const* d_in, const int* in_sizes, int n_in,
                              void* d_out, int out_size, void* d_ws, size_t ws_size,
                              hipStream_t stream)
{
  const float* data        = (const float*)d_in[0];
  const float* means       = (const float*)d_in[1];
  const float* cov_parts   = (const float*)d_in[2];
  const float* log_weights = (const float*)d_in[3];

  const int npts   = in_sizes[0] / 16;
  const int ntiles = npts / 32;        // N = 2,000,000 divisible by 32

  _Float16* W        = (_Float16*)d_ws;                         // 18*64*8 halfs
  float*    partials = (float*)((char*)d_ws + 18432);           // 512 floats
  unsigned* counter  = (unsigned*)((char*)d_ws + 18432 + 3072); // 1 u32

  const int GRID = 512, BLOCK = 256;   // 2 blocks/CU, known-resident
  setup_kernel<<<32, 64, 0, stream>>>(means, cov_parts, log_weights, W, counter);
  main_kernel<<<GRID, BLOCK, 0, stream>>>(data, W, partials, counter,
                                          (float*)d_out,
                                          LN2_D / (2.0 * (double)npts), ntiles);
}

// Round 6
// 201.615 us; speedup vs baseline: 1.4826x; 1.0772x over previous
//
#include <hip/hip_runtime.h>
#include <math.h>

// ---------------------------------------------------------------------------
// GMM log-likelihood, N=2M x D=16, K=32, out = mean_n logsumexp_k loglik[n,k]
//
// loglik[n,k] = sum_{ij} (-0.5 P_ij) x_i x_j + (P mu)_i x_i + c_k  (log2 dom.)
// LINEAR in phi(x) = [ x_i*x_j (256), x_i (16), 1 ] -> 18 K16-chunks of one
// chained mfma_f32_32x32x16_f16 (M=32 = all comps; c_k folded in as chunk 17).
// C layout (HW-verified): col=lane&31 (point), row=(reg&3)+8*(reg>>2)+4*(lane>>5).
// Lane pair (l, l^32) holds all 32 comps of a point; combined via
// v_permlane32_swap (VALU-only).
//
// R12: R11 regressed (217 vs R6/R7's 202); every fused-reduce round (R8/R9/
// R11) was worse than the plain 3-dispatch rounds -> revert to R7 wholesale.
// Counter identity from R9 (MfmaUtil = sum-SIMD busy / CU-cyc: 35.1k/180k =
// 19.5% matches measured 19.7%) gives per-SIMD issue-busy ~670 of 2950 cyc
// per tile-pair; each wave stalls ~2300 cyc/tile > 2 load latencies ->
// VMEM latency/request/occupancy theories all falsified (R9/R10/R11).
// Remaining fit: the 18-deep DEPENDENT MFMA chain (C-in = prev D-out,
// ~40 cyc/link = ~720 cyc) + ~200 cyc serial epilogue chain ~= the observed
// per-wave wall. Fix (only change vs R7): (1) dual accumulators - even
// chunks->acc0, odd->acc1: two independent 9-link chains the SIMD can
// interleave; merge = 16 v_add. (2) tree-shaped max/exp/sum epilogue.
// Predict: main ~45 -> ~28-33 us, total ~185-192, MfmaUtil/VALUBusy up
// ~1.4x, no spill (R9 fit dual-acc at VGPR 76). Null (total ~202) kills the
// chain theory -> structure is at its balanced floor; declare plateau.
// ---------------------------------------------------------------------------

#define LOG_2PI 1.8378770664093453f
#define INV_LN2 1.4426950408889634f
#define LN2_D   0.6931471805599453

typedef float    float4v __attribute__((ext_vector_type(4)));
typedef float    f32x16  __attribute__((ext_vector_type(16)));
typedef _Float16 f16x8   __attribute__((ext_vector_type(8)));
typedef _Float16 f16x2   __attribute__((ext_vector_type(2)));
typedef unsigned u32x2   __attribute__((ext_vector_type(2)));

union H8 { f16x8 h8; f16x2 h2[4]; };

#if __has_builtin(__builtin_amdgcn_exp2f)
#define EXP2F(x) __builtin_amdgcn_exp2f(x)
#else
#define EXP2F(x) exp2f(x)
#endif
#if __has_builtin(__builtin_amdgcn_logf)
#define LOG2F(x) __builtin_amdgcn_logf(x)
#else
#define LOG2F(x) log2f(x)
#endif

static __device__ __forceinline__ f16x2 pk2(float a, float b) {
#if __has_builtin(__builtin_amdgcn_cvt_pkrtz)
  return __builtin_bit_cast(f16x2, __builtin_amdgcn_cvt_pkrtz(a, b));
#else
  f16x2 r; r[0] = (_Float16)a; r[1] = (_Float16)b; return r;
#endif
}

// value of x in partner lane (lane ^ 32), VALU-only on gfx950
static __device__ __forceinline__ float partner32(float x, bool lo) {
#if __has_builtin(__builtin_amdgcn_permlane32_swap)
  unsigned u = __builtin_bit_cast(unsigned, x);
  u32x2 r = __builtin_amdgcn_permlane32_swap(u, u, false, false);
  return __builtin_bit_cast(float, lo ? r[1] : r[0]);
#else
  return __shfl_xor(x, 32, 64);
#endif
}

// dword select (works for f16x2 payloads)
static __device__ __forceinline__ f16x2 sel2(bool c, f16x2 a, f16x2 b) {
  unsigned ua = __builtin_bit_cast(unsigned, a);
  unsigned ub = __builtin_bit_cast(unsigned, b);
  return __builtin_bit_cast(f16x2, c ? ua : ub);
}

// ---------------------------------------------------------------------------
// Setup: per component k: cov = A A^T, Cholesky L, Linv, P = Linv^T Linv.
// W in 32x32x16 A-frag order: lane l holds A[m=l&31][k16 = 8*(l>>5)+v],
// chunk c covers feature k = 16c + 8h + v.
// chunks 0..15: (i,j)=(c, 8h+v) -> -0.5/ln2 * P[i][j]
// chunk 16: linear, feature i=8h+v -> (P mu)_i / ln2
// chunk 17: constant, slot (h=0,v=0) -> c2[m]; all other slots 0
// ---------------------------------------------------------------------------
__global__ void setup_kernel(const float* __restrict__ means,
                             const float* __restrict__ cov_parts,
                             const float* __restrict__ log_weights,
                             _Float16* __restrict__ W)
{
  const int k = blockIdx.x;
  const int i = threadIdx.x;

  __shared__ float sA[16][17];
  __shared__ float sC[16][17];
  __shared__ float sMu[16];
  __shared__ float sR[16];

  if (i < 16) {
    #pragma unroll
    for (int j = 0; j < 16; ++j) sA[i][j] = cov_parts[(k*16 + i)*16 + j];
    sMu[i] = means[k*16 + i];
  }
  __syncthreads();

  if (i < 16) {
    #pragma unroll
    for (int j = 0; j < 16; ++j) {
      float acc = 0.f;
      #pragma unroll
      for (int l = 0; l < 16; ++l) acc += sA[i][l] * sA[j][l];
      sC[i][j] = acc;
    }
  }
  __syncthreads();

  for (int j = 0; j < 16; ++j) {
    if (i == j) {
      float d = sC[j][j];
      for (int l = 0; l < j; ++l) d -= sC[j][l]*sC[j][l];
      sC[j][j] = sqrtf(d);
    }
    __syncthreads();
    if (i < 16 && i > j) {
      float a = sC[i][j];
      for (int l = 0; l < j; ++l) a -= sC[i][l]*sC[j][l];
      sC[i][j] = a / sC[j][j];
    }
    __syncthreads();
  }

  if (i < 16) {
    float y[16];
    #pragma unroll
    for (int r = 0; r < 16; ++r) {
      float a = (r == i) ? 1.f : 0.f;
      #pragma unroll
      for (int l = 0; l < r; ++l) a -= sC[r][l] * y[l];
      y[r] = a / sC[r][r];
    }
    #pragma unroll
    for (int r = 0; r < 16; ++r) sA[r][i] = y[r];
  }
  __syncthreads();

  if (i < 16) {
    float p[16];
    #pragma unroll
    for (int j = 0; j < 16; ++j) {
      float acc = 0.f;
      #pragma unroll
      for (int l = 0; l < 16; ++l) acc += sA[l][i] * sA[l][j];
      p[j] = acc;
    }
    float ri = 0.f;
    #pragma unroll
    for (int j = 0; j < 16; ++j) ri += p[j] * sMu[j];
    sR[i] = ri;

    #pragma unroll
    for (int j = 0; j < 16; ++j) {
      W[(size_t)(i*64 + (k + 32*(j >> 3)))*8 + (j & 7)] =
          (_Float16)(-0.5f * INV_LN2 * p[j]);
    }
    W[(size_t)(16*64 + (k + 32*(i >> 3)))*8 + (i & 7)] =
        (_Float16)(INV_LN2 * ri);
  }
  __syncthreads();

  if (i == 0) {
    float logdet = 0.f;
    #pragma unroll
    for (int j = 0; j < 16; ++j) logdet += __logf(sC[j][j]);
    float mupmu = 0.f;
    #pragma unroll
    for (int j = 0; j < 16; ++j) mupmu += sMu[j] * sR[j];
    float lw = log_weights[k];
    float c2v = INV_LN2 * (-0.5f*(mupmu + 16.f*LOG_2PI) - logdet + lw*lw);
    #pragma unroll
    for (int v = 0; v < 8; ++v) {
      W[(size_t)(17*64 + k)*8 + v]      = (v == 0) ? (_Float16)c2v : (_Float16)0.f;
      W[(size_t)(17*64 + k + 32)*8 + v] = (_Float16)0.f;
    }
  }
}

// ---------------------------------------------------------------------------
__global__ __launch_bounds__(256, 2) void main_kernel(
    const float* __restrict__ data,
    const _Float16* __restrict__ W,
    float* __restrict__ partials,
    int ntiles)
{
  const int lane = threadIdx.x & 63;
  const int n32  = lane & 31;
  const bool lo  = lane < 32;
  const int gwave  = (int)((blockIdx.x * blockDim.x + threadIdx.x) >> 6);
  const int nwaves = (int)((gridDim.x * blockDim.x) >> 6);

  // W fragments resident in registers for the whole kernel (72 regs)
  f16x8 Wf[18];
  #pragma unroll
  for (int c = 0; c < 18; ++c)
    Wf[c] = *(const f16x8*)(W + (size_t)(c*64 + lane)*8);

  // constant B fragment for the c2 chunk: slot (h=0,v=0) = 1
  H8 bC;
  #pragma unroll
  for (int j = 0; j < 4; ++j) bC.h2[j] = pk2(0.f, 0.f);
  if (lo) bC.h2[0] = pk2(1.f, 0.f);

  float accsum = 0.f;

  // tile t covers points [t*32, t*32+32); lane pair (l, l^32) share point n32
  const char* ptr = (const char*)data + ((size_t)gwave*2048 + (size_t)n32*64);
  const size_t step = (size_t)nwaves * 2048;

  float4v p0, p1, p2, p3;
  if (gwave < ntiles) {
    p0 = *(const float4v*)(ptr);      p1 = *(const float4v*)(ptr + 16);
    p2 = *(const float4v*)(ptr + 32); p3 = *(const float4v*)(ptr + 48);
  }

  for (int t = gwave; t < ntiles; t += nwaves) {
    // convert to f16 pairs: xh[q] = (x[2q], x[2q+1]); frees p* for prefetch
    f16x2 xh[8];
    xh[0] = pk2(p0[0], p0[1]); xh[1] = pk2(p0[2], p0[3]);
    xh[2] = pk2(p1[0], p1[1]); xh[3] = pk2(p1[2], p1[3]);
    xh[4] = pk2(p2[0], p2[1]); xh[5] = pk2(p2[2], p2[3]);
    xh[6] = pk2(p3[0], p3[1]); xh[7] = pk2(p3[2], p3[3]);

    ptr += step;
    if (t + nwaves < ntiles) {          // wave-uniform prefetch of next tile
      p0 = *(const float4v*)(ptr);      p1 = *(const float4v*)(ptr + 16);
      p2 = *(const float4v*)(ptr + 32); p3 = *(const float4v*)(ptr + 48);
    }

    // second factors for this lane half: xs[j] = xh[4h + j]
    f16x2 xs[4];
    #pragma unroll
    for (int j = 0; j < 4; ++j) xs[j] = sel2(lo, xh[j], xh[4+j]);

    // dual accumulators: even chunks -> acc0, odd -> acc1. Two independent
    // 9-link MFMA dependent chains the SIMD can interleave (vs 18 serial).
    f32x16 acc0, acc1;
    #pragma unroll
    for (int r = 0; r < 16; ++r) { acc0[r] = 0.f; acc1[r] = 0.f; }

    #pragma unroll
    for (int c = 0; c < 16; ++c) {
      _Float16 xi = xh[c >> 1][c & 1];
      H8 b;
      #pragma unroll
      for (int j = 0; j < 4; ++j) b.h2[j] = xs[j] * xi;  // v_pk_mul_f16
      if (c & 1)
        acc1 = __builtin_amdgcn_mfma_f32_32x32x16_f16(Wf[c], b.h8, acc1, 0, 0, 0);
      else
        acc0 = __builtin_amdgcn_mfma_f32_32x32x16_f16(Wf[c], b.h8, acc0, 0, 0, 0);
    }
    {   // linear chunk -> acc1
      H8 b;
      #pragma unroll
      for (int j = 0; j < 4; ++j) b.h2[j] = xs[j];
      acc1 = __builtin_amdgcn_mfma_f32_32x32x16_f16(Wf[16], b.h8, acc1, 0, 0, 0);
    }
    // c2 chunk -> acc0
    acc0 = __builtin_amdgcn_mfma_f32_32x32x16_f16(Wf[17], bC.h8, acc0, 0, 0, 0);

    f32x16 acc = acc0 + acc1;   // 16 v_add_f32 merge

    // epilogue: logsumexp (log2 domain), tree-shaped to shorten dep chains
    float mx0 = fmaxf(acc[0],  acc[8]);
    float mx1 = fmaxf(acc[1],  acc[9]);
    float mx2 = fmaxf(acc[2],  acc[10]);
    float mx3 = fmaxf(acc[3],  acc[11]);
    float mx4 = fmaxf(acc[4],  acc[12]);
    float mx5 = fmaxf(acc[5],  acc[13]);
    float mx6 = fmaxf(acc[6],  acc[14]);
    float mx7 = fmaxf(acc[7],  acc[15]);
    mx0 = fmaxf(mx0, mx4); mx1 = fmaxf(mx1, mx5);
    mx2 = fmaxf(mx2, mx6); mx3 = fmaxf(mx3, mx7);
    mx0 = fmaxf(mx0, mx2); mx1 = fmaxf(mx1, mx3);
    float m = fmaxf(mx0, mx1);
    m = fmaxf(m, partner32(m, lo));

    float e0  = EXP2F(acc[0]  - m), e1  = EXP2F(acc[1]  - m);
    float e2  = EXP2F(acc[2]  - m), e3  = EXP2F(acc[3]  - m);
    float e4  = EXP2F(acc[4]  - m), e5  = EXP2F(acc[5]  - m);
    float e6  = EXP2F(acc[6]  - m), e7  = EXP2F(acc[7]  - m);
    float e8  = EXP2F(acc[8]  - m), e9  = EXP2F(acc[9]  - m);
    float e10 = EXP2F(acc[10] - m), e11 = EXP2F(acc[11] - m);
    float e12 = EXP2F(acc[12] - m), e13 = EXP2F(acc[13] - m);
    float e14 = EXP2F(acc[14] - m), e15 = EXP2F(acc[15] - m);
    e0 += e8;  e1 += e9;  e2 += e10; e3 += e11;
    e4 += e12; e5 += e13; e6 += e14; e7 += e15;
    e0 += e4;  e1 += e5;  e2 += e6;  e3 += e7;
    e0 += e2;  e1 += e3;
    float s = e0 + e1;
    s += partner32(s, lo);
    accsum += m + LOG2F(s);
  }

  #pragma unroll
  for (int off = 1; off <= 32; off <<= 1)
    accsum += __shfl_xor(accsum, off, 64);

  __shared__ float wsum[4];
  const int wid = (int)(threadIdx.x >> 6);
  if ((threadIdx.x & 63) == 0) wsum[wid] = accsum;
  __syncthreads();
  if (threadIdx.x == 0)
    partials[blockIdx.x] = wsum[0] + wsum[1] + wsum[2] + wsum[3];
}

// ---------------------------------------------------------------------------
__global__ void reduce_kernel(const float* __restrict__ partials, int n,
                              float* __restrict__ out, double scale)
{
  __shared__ double sd[256];
  double a = 0.0;
  for (int idx = threadIdx.x; idx < n; idx += 256) a += (double)partials[idx];
  sd[threadIdx.x] = a;
  __syncthreads();
  for (int s = 128; s > 0; s >>= 1) {
    if ((int)threadIdx.x < s) sd[threadIdx.x] += sd[threadIdx.x + s];
    __syncthreads();
  }
  if (threadIdx.x == 0) out[0] = (float)(sd[0] * scale);
}

extern "C" void kernel_launch(void* const* d_in, const int* in_sizes, int n_in,
                              void* d_out, int out_size, void* d_ws, size_t ws_size,
                              hipStream_t stream)
{
  const float* data        = (const float*)d_in[0];
  const float* means       = (const float*)d_in[1];
  const float* cov_parts   = (const float*)d_in[2];
  const float* log_weights = (const float*)d_in[3];

  const int npts   = in_sizes[0] / 16;
  const int ntiles = npts / 32;        // N = 2,000,000 divisible by 32

  _Float16* W        = (_Float16*)d_ws;                      // 18*64*8 halfs
  float*    partials = (float*)((char*)d_ws + 18432);        // 512 floats

  const int GRID = 512, BLOCK = 256;   // 2 blocks/CU, known-resident
  setup_kernel<<<32, 64, 0, stream>>>(means, cov_parts, log_weights, W);
  main_kernel<<<GRID, BLOCK, 0, stream>>>(data, W, partials, ntiles);
  reduce_kernel<<<1, 256, 0, stream>>>(partials, GRID, (float*)d_out,
                                       LN2_D / (2.0 * (double)npts));
}